// Round 9
// baseline (144.489 us; speedup 1.0000x reference)
//
#include <hip/hip_runtime.h>
#include <hip/hip_bf16.h>
#include <stdint.h>

// ===================================================================
// PriorLayer online BP scan, round 11. s_t = norm(diag(p_t) T s_{t-1}).
// R10 (rolled loops) = R9 = R7 = 52.4us: I-cache falsified. Per-epoch
// ~5700cyc invariant under body/waves/barriers/conflicts/code-size/ILP;
// all pipes <30%. Remaining hypotheses: H-latency (exposed per-wave
// latency, hideable by TLP) vs H-shared (invisible per-CU serializer).
// R3's "TLP = zero" null is CONFOUNDED: it ran the old 16-way-conflict
// SROW layout, whose serialized LDS-pipe bursts alone explain perfect
// 2-block serialization. Never retested since the R7 conflict fix.
// R11 = R10 VERBATIM with ONE variable: 2 independent blocks per CU.
//  - CLEN 16 -> 8, NBLK 256 -> 512, __launch_bounds__(256, 2).
//  - 2 blocks x 4 waves = 2 waves/SIMD from DIFFERENT blocks (no
//    shared barrier): block B issues while block A sits in
//    lgkmcnt/barrier. Shared pipes all <30% busy in current regime.
//  - Each block: 14 epochs (BURN=6). If TLP works: wall ~14 epochs
//    vs 22 -> ~35us dispatch. If it fails again (clean regime), the
//    per-CU serializer is confirmed as the floor.
// ===================================================================

#define DIM   256
#define SEQ   65536
#define G     16                    // chunks per block (MFMA cols)
#define CLEN  8                     // outputs per chunk
#define NBLK  (SEQ / (G * CLEN))    // 512 blocks -> 2 per CU
#define BURN  6
#define STEPS (BURN + CLEN)         // 14 (even — pairing relies on it)
#define NW    4
#define TPB   (NW * 64)             // 256
#define PGP   17                    // pZL padded row (f32x2)

typedef short bf16x8 __attribute__((ext_vector_type(8)));
typedef float f32x4  __attribute__((ext_vector_type(4)));
typedef float f32x2  __attribute__((ext_vector_type(2)));

static __device__ __forceinline__ unsigned short f2bf(float x) {
  __hip_bfloat16 h = __float2bfloat16(x);
  return *reinterpret_cast<unsigned short*>(&h);
}

// LDS-only barrier: do NOT drain vmcnt (global stores / prefetch loads
// stay in flight). lgkmcnt(0) orders all ds ops.
static __device__ __forceinline__ void lds_barrier() {
  asm volatile("s_waitcnt lgkmcnt(0)" ::: "memory");
  __builtin_amdgcn_s_barrier();
}

__global__ __launch_bounds__(TPB, 2)
void prior_scan_kernel(const float* __restrict__ probs,
                       const float* __restrict__ tp,
                       float* __restrict__ out) {
  // SB: double-buffered state, fragment-major SB[buf][kb][lane][j]
  //     (reads linear/conflict-free; writes scatter ~linear).
  // pZL: parity-buffered lane partials [par][n][g=w*4+quad].
  __shared__ __attribute__((aligned(16))) short SB[2][8][64][8];
  __shared__ __attribute__((aligned(16))) f32x2 pZL[2][G][PGP];

  const int tid  = threadIdx.x;
  const int w    = tid >> 6;
  const int lane = tid & 63;
  const int n    = lane & 15;       // chunk within block = MFMA col
  const int quad = lane >> 4;
  const int g    = blockIdx.x * G + n;   // global chunk id (per lane)

  // ---- T rows w*64..w*64+63 into A-fragments (128 VGPR, resident)
  //      A[rt][kb]: m=lane&15 -> row w*64+rt*16+m; k=quad*8+j
  bf16x8 A[4][8];
#pragma unroll
  for (int rt = 0; rt < 4; rt++) {
    const int row = w * 64 + rt * 16 + n;
#pragma unroll
    for (int kb = 0; kb < 8; kb++) {
      const float* p = tp + row * DIM + kb * 32 + quad * 8;
      f32x4 f0 = *reinterpret_cast<const f32x4*>(p);
      f32x4 f1 = *reinterpret_cast<const f32x4*>(p + 4);
      bf16x8 a;
#pragma unroll
      for (int j = 0; j < 4; j++) {
        a[j]     = (short)f2bf(f0[j]);
        a[4 + j] = (short)f2bf(f1[j]);
      }
      A[rt][kb] = a;
    }
  }

  // ---- init state buf 0 = uniform 1/256 (bf16-exact; scale-invariant)
  {
    ushort4 u; u.x = u.y = u.z = u.w = (unsigned short)0x3B80;
    ushort4* dst = reinterpret_cast<ushort4*>(&SB[0][0][0][0]) + tid * 4;
    dst[0] = u; dst[1] = u; dst[2] = u; dst[3] = u;   // 4096 shorts total
  }

  // ---- observation fragment loader (lane-owned, direct from global)
  auto loadp = [&](int s, int rt, bool clamp) -> f32x4 {
    int t = g * CLEN - BURN + s;
    if (clamp && t < 0) t = 0;      // value unused when t<0
    return *reinterpret_cast<const f32x4*>(
        probs + (size_t)t * DIM + w * 64 + rt * 16 + quad * 4);
  };

  // 2-deep register prefetch ring
  f32x4 pf[2][4];
#pragma unroll
  for (int rt = 0; rt < 4; rt++) {
    pf[0][rt] = loadp(0, rt, true);
    pf[1][rt] = loadp(1, rt, true);
  }

  __syncthreads();                  // A/pf are private; orders SB init

  float qp[4][4];                   // q of previous epoch (deferred norm)

  // --- full 256-dim matvec, this wave's 64 rows: q = (T @ u) .* p
  auto matvec = [&](int cur, float (&q)[4][4]) {
    bf16x8 B[8];
#pragma unroll
    for (int kb = 0; kb < 8; kb++)  // linear conflict-free b128
      B[kb] = *reinterpret_cast<const bf16x8*>(&SB[cur][kb][lane][0]);
    f32x4 aE[4], aO[4];
#pragma unroll
    for (int rt = 0; rt < 4; rt++) {
      aE[rt] = f32x4{0.f, 0.f, 0.f, 0.f};
      aO[rt] = f32x4{0.f, 0.f, 0.f, 0.f};
    }
#pragma unroll
    for (int kb = 0; kb < 8; kb += 2) {
#pragma unroll
      for (int rt = 0; rt < 4; rt++) {
        aE[rt] = __builtin_amdgcn_mfma_f32_16x16x32_bf16(A[rt][kb],     B[kb],     aE[rt], 0, 0, 0);
        aO[rt] = __builtin_amdgcn_mfma_f32_16x16x32_bf16(A[rt][kb + 1], B[kb + 1], aO[rt], 0, 0, 0);
      }
    }
#pragma unroll
    for (int rt = 0; rt < 4; rt++)
#pragma unroll
      for (int v = 0; v < 4; v++)   // C/D: row=rt*16+quad*4+v, col=n
        q[rt][v] = (aE[rt][v] + aO[rt][v]) * pf[cur][rt][v];
  };

  // write map: r=w*64+rt*16+quad*4+v -> kb=w*2+(rt>>1),
  //            qd=(rt&1)*2+(quad>>1), j=(quad&1)*4+v  (R7-verified)
  auto write_state = [&](int nxt, const float (&q)[4][4]) {
#pragma unroll
    for (int rt = 0; rt < 4; rt++) {
      ushort4 sp;
      sp.x = f2bf(q[rt][0] * 0.015625f);
      sp.y = f2bf(q[rt][1] * 0.015625f);
      sp.z = f2bf(q[rt][2] * 0.015625f);
      sp.w = f2bf(q[rt][3] * 0.015625f);
      *reinterpret_cast<ushort4*>(
          &SB[nxt][w * 2 + (rt >> 1)][((rt & 1) * 2 + (quad >> 1)) * 16 + n]
             [(quad & 1) * 4]) = sp;
    }
  };

  // --- deferred finalize of epoch e1 (partials in pZL[pbuf])
  auto finalize = [&](int pbuf, int e1) {
    float Z = 0.f, L = 0.f;
#pragma unroll
    for (int j = 0; j < 8; j++) {   // 16 f32x2 partials for chunk n
      f32x4 r = *reinterpret_cast<const f32x4*>(&pZL[pbuf][n][j * 2]);
      Z += r[0] + r[2];
      L += r[1] + r[3];
    }
    const float zi = __builtin_amdgcn_rcpf(Z);
    const int t1 = g * CLEN + (e1 - BURN);
#pragma unroll
    for (int rt = 0; rt < 4; rt++) {
      f32x4 o;
#pragma unroll
      for (int v = 0; v < 4; v++) o[v] = qp[rt][v] * zi;
      *reinterpret_cast<f32x4*>(
          out + (size_t)t1 * DIM + w * 64 + rt * 16 + quad * 4) = o;
    }
    if (tid < 16)                   // n == tid for these lanes
      out[(size_t)SEQ * DIM + t1] = __logf(Z) - L * zi;
  };

  // --- burn epoch: NO partials, NO finalize, NO qp carry
  auto burn_body = [&](int e, int cur, int nxt) {
    float q[4][4];
    matvec(cur, q);
#pragma unroll
    for (int rt = 0; rt < 4; rt++)
      pf[cur][rt] = loadp(e + 2, rt, true);   // e+2 <= BURN+1 < STEPS
    const int t = g * CLEN - BURN + e;
    if (t < 0) {                    // pre-start: hold uniform state
      ushort4 sp;
      sp.x = sp.y = sp.z = sp.w = (unsigned short)0x3B80;
#pragma unroll
      for (int rt = 0; rt < 4; rt++)
        *reinterpret_cast<ushort4*>(
            &SB[nxt][w * 2 + (rt >> 1)][((rt & 1) * 2 + (quad >> 1)) * 16 + n]
               [(quad & 1) * 4]) = sp;
    } else {
      write_state(nxt, q);
    }
    lds_barrier();
  };

  // --- output epoch: lane-private partials + deferred finalize of e-1
  auto main_body = [&](int e, int cur, int nxt) {
    float q[4][4];
    matvec(cur, q);
    int ps = e + 2; if (ps > STEPS - 1) ps = STEPS - 1;
#pragma unroll
    for (int rt = 0; rt < 4; rt++)
      pf[cur][rt] = loadp(ps, rt, false);     // t >= 0 for all mains
    write_state(nxt, q);

    float sz = 0.f, sl = 0.f;       // lane-private over 16 rows
#pragma unroll
    for (int rt = 0; rt < 4; rt++)
#pragma unroll
      for (int v = 0; v < 4; v++) {
        float qq = q[rt][v];
        sz += qq;
        sl += qq * __logf(qq + 1e-30f);
      }
    pZL[cur][n][w * 4 + quad] = f32x2{sz, sl};

    if (e > BURN) finalize(nxt, e - 1);       // nxt == (e-1)&1

#pragma unroll
    for (int rt = 0; rt < 4; rt++)
#pragma unroll
      for (int v = 0; v < 4; v++) qp[rt][v] = q[rt][v];
    lds_barrier();
  };

  // Rolled epoch loops (R10): hot code L1I-resident; cur/nxt stay
  // compile-time inside the even/odd pair.
#pragma clang loop unroll(disable)
  for (int e = 0; e < BURN; e += 2) {         // BURN even
    burn_body(e, 0, 1);
    burn_body(e + 1, 1, 0);
  }
#pragma clang loop unroll(disable)
  for (int e = BURN; e < STEPS; e += 2) {     // STEPS even, BURN even
    main_body(e, 0, 1);
    main_body(e + 1, 1, 0);
  }

  // --- tail: finalize epoch STEPS-1 (partials in pZL[(STEPS-1)&1])
  finalize((STEPS - 1) & 1, STEPS - 1);
}

extern "C" void kernel_launch(void* const* d_in, const int* in_sizes, int n_in,
                              void* d_out, int out_size, void* d_ws, size_t ws_size,
                              hipStream_t stream) {
  const float* probs = (const float*)d_in[0];   // (65536, 256)
  const float* tp    = (const float*)d_in[1];   // (256, 256)
  float* out         = (float*)d_out;           // 65536*256 probs + 65536 H

  hipLaunchKernelGGL(prior_scan_kernel, dim3(NBLK), dim3(TPB), 0, stream,
                     probs, tp, out);
}

// Round 11
// 142.007 us; speedup vs baseline: 1.0175x; 1.0175x over previous
//
#include <hip/hip_runtime.h>
#include <hip/hip_bf16.h>
#include <stdint.h>

// ===================================================================
// PriorLayer online BP scan, round 13. s_t = norm(diag(p_t) T s_{t-1}).
// R12 failed on a ONE-LINE addressing bug: matvec's p-fragment read
// dropped the w*64 row offset (probs output passed vacuously -- values
// ~0.004-0.05 << 0.109 threshold -- entropy at scale ~5.5 caught it).
// R13 = R12 with the fix. The hypothesis under test is unchanged:
// ELEVEN-ROUND RE-FIT shows wall = (FETCH+WRITE)/~2.25 TB/s for every
// variant (epoch count/body never mattered -- bytes did); the family
// is supply-limited by SCATTERED 64B-granule global access (MFMA
// fragment layout leaked into global I/O).
// R13 routes ALL global I/O as 1KB-contiguous rows via LDS staging:
//  - probs: wave w loads rows for chunks 4w..4w+3 contiguously into
//    regs at epoch e (step e+2), ds_writes to PT at e+1 (T14
//    issue-early/write-late); matvec reads p fragments from PT
//    (4-way b128, hidden under MFMAs). No new barriers.
//  - out: finalize ds_writes o fragments to OT[par]; next epoch (after
//    the existing barrier) waves stream 4x1KB contiguous rows to
//    global. Stores lag 2 epochs; drained after the loop.
//  - SB/matvec/partials/barrier discipline: R10 verbatim.
// ===================================================================

#define DIM   256
#define SEQ   65536
#define G     16                    // chunks per block (MFMA cols)
#define CLEN  16                    // outputs per chunk
#define NBLK  (SEQ / (G * CLEN))    // 256 blocks -> 1 per CU
#define BURN  6
#define STEPS (BURN + CLEN)         // 22 (even — pairing relies on it)
#define NW    4
#define TPB   (NW * 64)             // 256
#define PGP   17                    // pZL padded row (f32x2)
#define PROW  264                   // PT/OT padded row (f32)

#define SB_OFF  0                   // short[2][8][64][8]   = 16384 B
#define PT_OFF  16384               // float[2][16][264]    = 33792 B
#define OT_OFF  50176               // float[2][16][264]    = 33792 B
#define ZL_OFF  83968               // f32x2[2][16][17]     =  4352 B
#define LDS_BYTES 88320

typedef short bf16x8 __attribute__((ext_vector_type(8)));
typedef float f32x4  __attribute__((ext_vector_type(4)));
typedef float f32x2  __attribute__((ext_vector_type(2)));

static __device__ __forceinline__ unsigned short f2bf(float x) {
  __hip_bfloat16 h = __float2bfloat16(x);
  return *reinterpret_cast<unsigned short*>(&h);
}

// LDS-only barrier: do NOT drain vmcnt (global stores / prefetch loads
// stay in flight). lgkmcnt(0) orders all ds ops.
static __device__ __forceinline__ void lds_barrier() {
  asm volatile("s_waitcnt lgkmcnt(0)" ::: "memory");
  __builtin_amdgcn_s_barrier();
}

__global__ __launch_bounds__(TPB, 1)
void prior_scan_kernel(const float* __restrict__ probs,
                       const float* __restrict__ tp,
                       float* __restrict__ out) {
  extern __shared__ __align__(16) char lds_raw[];
  short* SBb = reinterpret_cast<short*>(lds_raw + SB_OFF);
  float* PTb = reinterpret_cast<float*>(lds_raw + PT_OFF);
  float* OTb = reinterpret_cast<float*>(lds_raw + OT_OFF);
  f32x2* ZLb = reinterpret_cast<f32x2*>(lds_raw + ZL_OFF);

  const int tid  = threadIdx.x;
  const int w    = tid >> 6;
  const int lane = tid & 63;
  const int n    = lane & 15;       // chunk within block = MFMA col
  const int quad = lane >> 4;
  const int cbase = blockIdx.x * G;
  const int g    = cbase + n;       // global chunk id (per lane)

  auto SB = [&](int buf, int kb, int l, int j) -> short* {
    return SBb + (((buf * 8 + kb) * 64 + l) * 8 + j);
  };
  auto PT = [&](int buf, int nn, int i) -> float* {
    return PTb + ((buf * 16 + nn) * PROW + i);
  };
  auto OT = [&](int buf, int nn, int i) -> float* {
    return OTb + ((buf * 16 + nn) * PROW + i);
  };

  // ---- T rows w*64..w*64+63 into A-fragments (resident)
  bf16x8 A[4][8];
#pragma unroll
  for (int rt = 0; rt < 4; rt++) {
    const int row = w * 64 + rt * 16 + n;
#pragma unroll
    for (int kb = 0; kb < 8; kb++) {
      const float* p = tp + row * DIM + kb * 32 + quad * 8;
      f32x4 f0 = *reinterpret_cast<const f32x4*>(p);
      f32x4 f1 = *reinterpret_cast<const f32x4*>(p + 4);
      bf16x8 a;
#pragma unroll
      for (int j = 0; j < 4; j++) {
        a[j]     = (short)f2bf(f0[j]);
        a[4 + j] = (short)f2bf(f1[j]);
      }
      A[rt][kb] = a;
    }
  }

  // ---- init state buf 0 = uniform 1/256 (bf16-exact; scale-invariant)
  {
    ushort4 u; u.x = u.y = u.z = u.w = (unsigned short)0x3B80;
    ushort4* dst = reinterpret_cast<ushort4*>(SBb) + tid * 4;
    dst[0] = u; dst[1] = u; dst[2] = u; dst[3] = u;   // 4096 shorts
  }

  // ---- contiguous row loader: wave w owns chunks 4w+j, full 1KB rows
  f32x4 P4[4];                      // staged rows for step s (regs)
  auto load_rows = [&](int s) {
#pragma unroll
    for (int j = 0; j < 4; j++) {
      int t = (cbase + 4 * w + j) * CLEN - BURN + s;
      if (t < 0) t = 0;             // value unused when t<0
      P4[j] = *reinterpret_cast<const f32x4*>(
          probs + (size_t)t * DIM + lane * 4);
    }
  };

  // ---- prologue: step 0 staged to PT[0]; step 1 in regs
  {
    f32x4 tmp[4];
#pragma unroll
    for (int j = 0; j < 4; j++) {
      int t = (cbase + 4 * w + j) * CLEN - BURN;   // s=0
      if (t < 0) t = 0;
      tmp[j] = *reinterpret_cast<const f32x4*>(
          probs + (size_t)t * DIM + lane * 4);
    }
#pragma unroll
    for (int j = 0; j < 4; j++)
      *reinterpret_cast<f32x4*>(PT(0, 4 * w + j, lane * 4)) = tmp[j];
    load_rows(1);
  }
  __syncthreads();                  // PT[0] + SB init visible

  float qp[4][4];                   // q of previous epoch (deferred norm)

  // --- full 256-dim matvec, this wave's 64 rows: q = (T @ u) .* p
  auto matvec = [&](int cur, float (&q)[4][4]) {
    bf16x8 B[8];
#pragma unroll
    for (int kb = 0; kb < 8; kb++)  // linear conflict-free b128
      B[kb] = *reinterpret_cast<const bf16x8*>(SB(cur, kb, lane, 0));
    f32x4 P[4];
#pragma unroll
    for (int rt = 0; rt < 4; rt++)  // p fragment: THIS WAVE'S rows (w*64 +)
      P[rt] = *reinterpret_cast<const f32x4*>(
          PT(cur, n, w * 64 + rt * 16 + quad * 4));
    f32x4 aE[4], aO[4];
#pragma unroll
    for (int rt = 0; rt < 4; rt++) {
      aE[rt] = f32x4{0.f, 0.f, 0.f, 0.f};
      aO[rt] = f32x4{0.f, 0.f, 0.f, 0.f};
    }
#pragma unroll
    for (int kb = 0; kb < 8; kb += 2) {
#pragma unroll
      for (int rt = 0; rt < 4; rt++) {
        aE[rt] = __builtin_amdgcn_mfma_f32_16x16x32_bf16(A[rt][kb],     B[kb],     aE[rt], 0, 0, 0);
        aO[rt] = __builtin_amdgcn_mfma_f32_16x16x32_bf16(A[rt][kb + 1], B[kb + 1], aO[rt], 0, 0, 0);
      }
    }
#pragma unroll
    for (int rt = 0; rt < 4; rt++)
#pragma unroll
      for (int v = 0; v < 4; v++)   // C/D: row=rt*16+quad*4+v, col=n
        q[rt][v] = (aE[rt][v] + aO[rt][v]) * P[rt][v];
  };

  // stage PT[nxt] (step e+1) from regs; issue loads for step e+2
  auto stagePT = [&](int e, int nxt) {
#pragma unroll
    for (int j = 0; j < 4; j++)
      *reinterpret_cast<f32x4*>(PT(nxt, 4 * w + j, lane * 4)) = P4[j];
    int s2 = e + 2; if (s2 > STEPS - 1) s2 = STEPS - 1;
    load_rows(s2);
  };

  // write map (R7-verified): r=w*64+rt*16+quad*4+v -> kb=w*2+(rt>>1),
  //            qd=(rt&1)*2+(quad>>1), j=(quad&1)*4+v
  auto write_state = [&](int nxt, const float (&q)[4][4]) {
#pragma unroll
    for (int rt = 0; rt < 4; rt++) {
      ushort4 sp;
      sp.x = f2bf(q[rt][0] * 0.015625f);
      sp.y = f2bf(q[rt][1] * 0.015625f);
      sp.z = f2bf(q[rt][2] * 0.015625f);
      sp.w = f2bf(q[rt][3] * 0.015625f);
      *reinterpret_cast<ushort4*>(
          SB(nxt, w * 2 + (rt >> 1),
             ((rt & 1) * 2 + (quad >> 1)) * 16 + n, (quad & 1) * 4)) = sp;
    }
  };

  // --- deferred finalize of step e1: o -> OT[pbuf]; entropy direct
  auto finalize = [&](int pbuf, int e1) {
    float Z = 0.f, L = 0.f;
    const f32x2* zl = ZLb + (pbuf * 16 + n) * PGP;
#pragma unroll
    for (int j = 0; j < 8; j++) {   // 16 f32x2 partials for chunk n
      f32x4 r = *reinterpret_cast<const f32x4*>(zl + j * 2);
      Z += r[0] + r[2];
      L += r[1] + r[3];
    }
    const float zi = __builtin_amdgcn_rcpf(Z);
#pragma unroll
    for (int rt = 0; rt < 4; rt++) {
      f32x4 o;
#pragma unroll
      for (int v = 0; v < 4; v++) o[v] = qp[rt][v] * zi;
      *reinterpret_cast<f32x4*>(
          OT(pbuf, n, w * 64 + rt * 16 + quad * 4)) = o;
    }
    if (tid < 16) {                 // n == tid for these lanes
      const int t1 = g * CLEN + (e1 - BURN);
      out[(size_t)SEQ * DIM + t1] = __logf(Z) - L * zi;
    }
  };

  // --- stream OT[pbuf] (step e1) to global: 1KB-contiguous per row
  auto stream_out = [&](int pbuf, int e1) {
#pragma unroll
    for (int j = 0; j < 4; j++) {
      const int nn = 4 * w + j;
      f32x4 v = *reinterpret_cast<const f32x4*>(OT(pbuf, nn, lane * 4));
      const int t1 = (cbase + nn) * CLEN + (e1 - BURN);
      *reinterpret_cast<f32x4*>(out + (size_t)t1 * DIM + lane * 4) = v;
    }
  };

  // --- burn epoch: NO partials, NO finalize, NO qp carry
  auto burn_body = [&](int e, int cur, int nxt) {
    float q[4][4];
    matvec(cur, q);
    stagePT(e, nxt);
    const int t = g * CLEN - BURN + e;
    if (t < 0) {                    // pre-start: hold uniform state
      ushort4 sp;
      sp.x = sp.y = sp.z = sp.w = (unsigned short)0x3B80;
#pragma unroll
      for (int rt = 0; rt < 4; rt++)
        *reinterpret_cast<ushort4*>(
            SB(nxt, w * 2 + (rt >> 1),
               ((rt & 1) * 2 + (quad >> 1)) * 16 + n, (quad & 1) * 4)) = sp;
    } else {
      write_state(nxt, q);
    }
    lds_barrier();
  };

  // --- output epoch: partials + stream(e-2) + finalize(e-1)
  auto main_body = [&](int e, int cur, int nxt) {
    float q[4][4];
    matvec(cur, q);
    stagePT(e, nxt);
    write_state(nxt, q);

    float sz = 0.f, sl = 0.f;       // lane-private over 16 rows
#pragma unroll
    for (int rt = 0; rt < 4; rt++)
#pragma unroll
      for (int v = 0; v < 4; v++) {
        float qq = q[rt][v];
        sz += qq;
        sl += qq * __logf(qq + 1e-30f);
      }
    *(ZLb + (cur * 16 + n) * PGP + (w * 4 + quad)) = f32x2{sz, sl};

    if (e >= BURN + 2) stream_out(cur, e - 2);  // OT[cur]=(e-2)&1, barrier'd
    if (e > BURN) finalize(nxt, e - 1);         // nxt == (e-1)&1

#pragma unroll
    for (int rt = 0; rt < 4; rt++)
#pragma unroll
      for (int v = 0; v < 4; v++) qp[rt][v] = q[rt][v];
    lds_barrier();
  };

  // Rolled epoch loops (R10): cur/nxt compile-time inside the pair.
#pragma clang loop unroll(disable)
  for (int e = 0; e < BURN; e += 2) {         // BURN even
    burn_body(e, 0, 1);
    burn_body(e + 1, 1, 0);
  }
#pragma clang loop unroll(disable)
  for (int e = BURN; e < STEPS; e += 2) {     // STEPS even, BURN even
    main_body(e, 0, 1);
    main_body(e + 1, 1, 0);
  }

  // --- tail: steps STEPS-2 and STEPS-1 still in OT/pZL
  stream_out((STEPS - 2) & 1, STEPS - 2);     // finalized at epoch STEPS-1
  finalize((STEPS - 1) & 1, STEPS - 1);       // qp holds last q; pZL[1]
  lds_barrier();                              // OT[1] cross-wave visible
  stream_out((STEPS - 1) & 1, STEPS - 1);
}

extern "C" void kernel_launch(void* const* d_in, const int* in_sizes, int n_in,
                              void* d_out, int out_size, void* d_ws, size_t ws_size,
                              hipStream_t stream) {
  const float* probs = (const float*)d_in[0];   // (65536, 256)
  const float* tp    = (const float*)d_in[1];   // (256, 256)
  float* out         = (float*)d_out;           // 65536*256 probs + 65536 H

  static bool configured = false;
  if (!configured) {
    hipFuncSetAttribute(reinterpret_cast<const void*>(prior_scan_kernel),
                        hipFuncAttributeMaxDynamicSharedMemorySize, LDS_BYTES);
    configured = true;
  }

  hipLaunchKernelGGL(prior_scan_kernel, dim3(NBLK), dim3(TPB), LDS_BYTES,
                     stream, probs, tp, out);
}